// Round 9
// baseline (51960.303 us; speedup 1.0000x reference)
//
#include <hip/hip_runtime.h>

// BasicMGU scan, XCD-local L2 dataflow with IF fallback.
// 8 batch-groups x 8 rows; group g = blockIdx&7 (native round-robin blockIdx->
// XCD mapping => all 16 WGs of a group share one XCD's L2). Exchange h and
// g=h*f as (tag16|bf16hi),(tag16|bf16lo) dword pairs, parity double-buffered.
// Producer: PLAIN stores (write-through L1 -> local L2), fire-and-forget.
// Consumer: poll the data with sc0 loads (L1-bypass, L2-served) for 16 fast
// iterations; if still stale (grouping/coherence assumption wrong), escalate
// permanently to sc0 sc1 IF polling (R8-proven) -- cannot hang.
// End-of-kernel agent release fence writes back dirty exchange lines so the
// next replay's memset starts clean. Weights AGPR-pinned; 3-term MFMA split.

typedef __bf16 bf16;
typedef __attribute__((ext_vector_type(8))) __bf16 bf16x8;
typedef __attribute__((ext_vector_type(4))) float f32x4;
typedef __attribute__((ext_vector_type(4))) unsigned u32x4;
typedef __attribute__((ext_vector_type(2))) unsigned u32x2;

#define MFMA16(a, b, c) __builtin_amdgcn_mfma_f32_16x16x32_bf16((a), (b), (c), 0, 0, 0)
#define WB(q) __builtin_bit_cast(bf16x8, q)

constexpr int Tc = 1024, Dc = 512, Uc = 512;
constexpr int GRPS = 8, GR = 8, NWG = GRPS * 16;  // 128 WGs

constexpr size_t HPAR = (size_t)GRPS * GR * Uc * 2;  // dwords per parity buffer
constexpr size_t WS_ZERO = 4 * HPAR * 4;             // H[2] + G[2] = 1 MiB

// one lane's 32 values (64 tagged dwords) as 16 dwordx4 — L2-served (sc0)
__device__ inline void load16qL(const unsigned* p, u32x4 b[16]) {
  asm volatile(
      "global_load_dwordx4 %0,  %16, off sc0\n\t"
      "global_load_dwordx4 %1,  %16, off offset:16 sc0\n\t"
      "global_load_dwordx4 %2,  %16, off offset:32 sc0\n\t"
      "global_load_dwordx4 %3,  %16, off offset:48 sc0\n\t"
      "global_load_dwordx4 %4,  %16, off offset:256 sc0\n\t"
      "global_load_dwordx4 %5,  %16, off offset:272 sc0\n\t"
      "global_load_dwordx4 %6,  %16, off offset:288 sc0\n\t"
      "global_load_dwordx4 %7,  %16, off offset:304 sc0\n\t"
      "global_load_dwordx4 %8,  %16, off offset:512 sc0\n\t"
      "global_load_dwordx4 %9,  %16, off offset:528 sc0\n\t"
      "global_load_dwordx4 %10, %16, off offset:544 sc0\n\t"
      "global_load_dwordx4 %11, %16, off offset:560 sc0\n\t"
      "global_load_dwordx4 %12, %16, off offset:768 sc0\n\t"
      "global_load_dwordx4 %13, %16, off offset:784 sc0\n\t"
      "global_load_dwordx4 %14, %16, off offset:800 sc0\n\t"
      "global_load_dwordx4 %15, %16, off offset:816 sc0"
      : "=&v"(b[0]), "=&v"(b[1]), "=&v"(b[2]), "=&v"(b[3]),
        "=&v"(b[4]), "=&v"(b[5]), "=&v"(b[6]), "=&v"(b[7]),
        "=&v"(b[8]), "=&v"(b[9]), "=&v"(b[10]), "=&v"(b[11]),
        "=&v"(b[12]), "=&v"(b[13]), "=&v"(b[14]), "=&v"(b[15])
      : "v"(p) : "memory");
}

// same, IF-served (sc0 sc1) — the R8-proven fallback
__device__ inline void load16qF(const unsigned* p, u32x4 b[16]) {
  asm volatile(
      "global_load_dwordx4 %0,  %16, off sc0 sc1\n\t"
      "global_load_dwordx4 %1,  %16, off offset:16 sc0 sc1\n\t"
      "global_load_dwordx4 %2,  %16, off offset:32 sc0 sc1\n\t"
      "global_load_dwordx4 %3,  %16, off offset:48 sc0 sc1\n\t"
      "global_load_dwordx4 %4,  %16, off offset:256 sc0 sc1\n\t"
      "global_load_dwordx4 %5,  %16, off offset:272 sc0 sc1\n\t"
      "global_load_dwordx4 %6,  %16, off offset:288 sc0 sc1\n\t"
      "global_load_dwordx4 %7,  %16, off offset:304 sc0 sc1\n\t"
      "global_load_dwordx4 %8,  %16, off offset:512 sc0 sc1\n\t"
      "global_load_dwordx4 %9,  %16, off offset:528 sc0 sc1\n\t"
      "global_load_dwordx4 %10, %16, off offset:544 sc0 sc1\n\t"
      "global_load_dwordx4 %11, %16, off offset:560 sc0 sc1\n\t"
      "global_load_dwordx4 %12, %16, off offset:768 sc0 sc1\n\t"
      "global_load_dwordx4 %13, %16, off offset:784 sc0 sc1\n\t"
      "global_load_dwordx4 %14, %16, off offset:800 sc0 sc1\n\t"
      "global_load_dwordx4 %15, %16, off offset:816 sc0 sc1"
      : "=&v"(b[0]), "=&v"(b[1]), "=&v"(b[2]), "=&v"(b[3]),
        "=&v"(b[4]), "=&v"(b[5]), "=&v"(b[6]), "=&v"(b[7]),
        "=&v"(b[8]), "=&v"(b[9]), "=&v"(b[10]), "=&v"(b[11]),
        "=&v"(b[12]), "=&v"(b[13]), "=&v"(b[14]), "=&v"(b[15])
      : "v"(p) : "memory");
}

__device__ inline bool freshq(const u32x4* b, unsigned tag) {
  unsigned acc = 0;
#pragma unroll
  for (int i = 0; i < 16; ++i) {
    u32x4 v = b[i];
    acc |= (v[0] ^ tag) | (v[1] ^ tag) | (v[2] ^ tag) | (v[3] ^ tag);
  }
  return (acc & 0xFFFF0000u) == 0;
}

// data poll: 16 fast L2 iterations, then permanent IF fallback (no hang)
__device__ inline void pollq(const unsigned* p, unsigned tag, u32x4 b[16]) {
  for (int i = 0; i < 16; ++i) {
    load16qL(p, b);
    asm volatile("s_waitcnt vmcnt(0)" ::: "memory");
    __builtin_amdgcn_sched_barrier(0);  // rule 18
    if (__ballot(!freshq(b, tag)) == 0) return;
  }
  for (;;) {
    load16qF(p, b);
    asm volatile("s_waitcnt vmcnt(0)" ::: "memory");
    __builtin_amdgcn_sched_barrier(0);
    if (__ballot(!freshq(b, tag)) == 0) return;
  }
}

// quad jj holds [tag|hi(2jj), tag|lo(2jj), tag|hi(2jj+1), tag|lo(2jj+1)]
__device__ inline void mk8(const u32x4* q, bf16x8& fh, bf16x8& fl) {
  union { unsigned d[4]; bf16x8 v; } H, L;
#pragma unroll
  for (int jj = 0; jj < 4; ++jj) {
    H.d[jj] = (q[jj][0] & 0xFFFFu) | (q[jj][2] << 16);
    L.d[jj] = (q[jj][1] & 0xFFFFu) | (q[jj][3] << 16);
  }
  fh = H.v;
  fl = L.v;
}

// PLAIN fire-and-forget store: write-through L1 -> producer's XCD L2
__device__ inline void store_pair(unsigned* p, unsigned tag, float v) {
  bf16 hi = (bf16)v;
  bf16 lo = (bf16)(v - (float)hi);
  u32x2 d;
  d[0] = tag | (unsigned)__builtin_bit_cast(unsigned short, hi);
  d[1] = tag | (unsigned)__builtin_bit_cast(unsigned short, lo);
  asm volatile("global_store_dwordx2 %0, %1, off" ::"v"(p), "v"(d) : "memory");
}

__global__ __launch_bounds__(256, 1)
void mgu_kernel(const float* __restrict__ x,
                const float* __restrict__ Wk, const float* __restrict__ Wr,
                const float* __restrict__ br,
                const float* __restrict__ Wu, const float* __restrict__ Wur,
                const float* __restrict__ bur,
                unsigned* __restrict__ ws0, float* __restrict__ out) {
  __shared__ float red[2][4][2][16][16];  // [phase][wave][ct][row][col16]

  unsigned* Hb = ws0;               // H[2][...]
  unsigned* Gb = ws0 + 2 * HPAR;    // G[2][...]

  const int wg = blockIdx.x;
  const int g = wg & 7, cw = wg >> 3;
  const int c0 = cw * 32;
  const int tid = threadIdx.x;
  const int w = tid >> 6, lane = tid & 63;
  const int dcol = lane & 15, kq = lane >> 4;
  const int rrow = dcol & 7;              // real batch row (dup for MFMA M=16)
  const int kbase = w * 128 + kq * 8;

  // ---- weights into AGPR-pinned registers. Wr/Wur hi+lo; Wk/Wu hi only.
  f32x4 WKH[2][4], WRH[2][4], WRL[2][4], WUH[2][4], WQH[2][4], WQL[2][4];
#pragma unroll
  for (int ct = 0; ct < 2; ++ct) {
    const int col = c0 + ct * 16 + dcol;
#pragma unroll
    for (int kb = 0; kb < 4; ++kb) {
      union { bf16x8 v; f32x4 f; } a_, b_, c_, d_, e_, q_;
#pragma unroll
      for (int j = 0; j < 8; ++j) {
        const size_t ko = (size_t)(kbase + kb * 32 + j) * Uc + col;
        { float v = Wk[ko]; a_.v[j] = (bf16)v; }
        { float v = Wr[ko]; bf16 h0 = (bf16)v; b_.v[j] = h0; c_.v[j] = (bf16)(v - (float)h0); }
        { float v = Wu[ko]; d_.v[j] = (bf16)v; }
        { float v = Wur[ko]; bf16 h0 = (bf16)v; e_.v[j] = h0; q_.v[j] = (bf16)(v - (float)h0); }
      }
      WKH[ct][kb] = a_.f; WRH[ct][kb] = b_.f; WRL[ct][kb] = c_.f;
      WUH[ct][kb] = d_.f; WQH[ct][kb] = e_.f; WQL[ct][kb] = q_.f;
    }
  }
#pragma unroll
  for (int ct = 0; ct < 2; ++ct)
#pragma unroll
    for (int kb = 0; kb < 4; ++kb)
      asm volatile("" : "+a"(WKH[ct][kb]), "+a"(WRH[ct][kb]), "+a"(WRL[ct][kb]),
                       "+a"(WUH[ct][kb]), "+a"(WQH[ct][kb]), "+a"(WQL[ct][kb]));

  // ---- wave-0 finalizer: lane -> (colL, rows 2r+sub)
  const int sub = lane >> 5, colL = lane & 31;
  const int fct = colL >> 4, fc16 = colL & 15;
  const float brv = br[c0 + colL], burv = bur[c0 + colL];

  const size_t ldoff = ((size_t)(g * GR + rrow) * Uc + kbase) * 2;
  size_t stoff[4];
#pragma unroll
  for (int r = 0; r < 4; ++r)
    stoff[r] = ((size_t)(g * GR + 2 * r + sub) * Uc + c0 + colL) * 2;

  const float* xptr = x + (size_t)(g * GR + rrow) * Tc * Dc + kbase;

  float h_keep[4] = {0.f, 0.f, 0.f, 0.f}, f_keep[4];
  f32x4 axk[2], axu[2];
  f32x4 xr[8];

  // compute axk/axu from xr (x(t)); called right after the h(t) poll
  auto do_x_mfma = [&]() {
    bf16x8 xh[4], xl[4];
#pragma unroll
    for (int kb = 0; kb < 4; ++kb) {
      f32x4 a = xr[2 * kb], b = xr[2 * kb + 1];
#pragma unroll
      for (int j = 0; j < 4; ++j) {
        bf16 h0 = (bf16)a[j]; xh[kb][j] = h0; xl[kb][j] = (bf16)(a[j] - (float)h0);
        bf16 h1 = (bf16)b[j]; xh[kb][4 + j] = h1; xl[kb][4 + j] = (bf16)(b[j] - (float)h1);
      }
    }
#pragma unroll
    for (int ct = 0; ct < 2; ++ct) {
      f32x4 k0 = {0.f, 0.f, 0.f, 0.f}, k1 = k0, u0 = k0, u1 = k0;
#pragma unroll
      for (int kb = 0; kb < 4; ++kb) {
        k0 = MFMA16(xh[kb], WB(WKH[ct][kb]), k0);
        k1 = MFMA16(xl[kb], WB(WKH[ct][kb]), k1);
        u0 = MFMA16(xh[kb], WB(WUH[ct][kb]), u0);
        u1 = MFMA16(xl[kb], WB(WUH[ct][kb]), u1);
      }
      axk[ct] = k0 + k1;
      axu[ct] = u0 + u1;
    }
  };

  {  // prologue: x(0) loads (consumed after the first h-poll)
    const float* xp = xptr;
#pragma unroll
    for (int kb = 0; kb < 4; ++kb) {
      xr[2 * kb] = *(const f32x4*)(xp + kb * 32);
      xr[2 * kb + 1] = *(const f32x4*)(xp + kb * 32 + 4);
    }
  }

  for (int t = 0; t < Tc; ++t) {
    const unsigned tag0 = (unsigned)t << 16, tag1 = (unsigned)(t + 1) << 16;
    const unsigned* Hrd = Hb + (size_t)(t & 1) * HPAR + ldoff;
    const unsigned* Grd = Gb + (size_t)((t + 1) & 1) * HPAR + ldoff;
    unsigned* Gwr = Gb + (size_t)((t + 1) & 1) * HPAR;
    unsigned* Hwr = Hb + (size_t)((t + 1) & 1) * HPAR;
    u32x4 b[16];

    // ---- phase 1: poll h(t), then x(t) MFMAs, then issue x(t+1), then h@Wr
    pollq(Hrd, tag0, b);
    do_x_mfma();                     // x(t) -> axk/axu (xr free after this)
    if (t + 1 < Tc) {                // x(t+1) into xr; drains during phase 2
      const float* xp = xptr + (size_t)(t + 1) * Dc;
#pragma unroll
      for (int kb = 0; kb < 4; ++kb) {
        xr[2 * kb] = *(const f32x4*)(xp + kb * 32);
        xr[2 * kb + 1] = *(const f32x4*)(xp + kb * 32 + 4);
      }
    }
    {
      bf16x8 fh[4], fl[4];
#pragma unroll
      for (int kb = 0; kb < 4; ++kb) mk8(&b[kb * 4], fh[kb], fl[kb]);
#pragma unroll
      for (int ct = 0; ct < 2; ++ct) {
        f32x4 r0 = {0.f, 0.f, 0.f, 0.f}, r1 = r0, r2 = r0;
#pragma unroll
        for (int kb = 0; kb < 4; ++kb) {
          r0 = MFMA16(fh[kb], WB(WRH[ct][kb]), r0);
          r1 = MFMA16(fl[kb], WB(WRH[ct][kb]), r1);
          r2 = MFMA16(fh[kb], WB(WRL[ct][kb]), r2);
        }
        f32x4 r = axk[ct] + r0 + r1 + r2;
#pragma unroll
        for (int i = 0; i < 4; ++i) red[0][w][ct][kq * 4 + i][dcol] = r[i];
      }
    }
    __syncthreads();
    if (w == 0) {  // finalize f for all 8 rows; plain fire-and-forget g store
#pragma unroll
      for (int r = 0; r < 4; ++r) {
        const int row = 2 * r + sub;
        float af = red[0][0][fct][row][fc16] + red[0][1][fct][row][fc16] +
                   red[0][2][fct][row][fc16] + red[0][3][fct][row][fc16] + brv;
        float f = __builtin_amdgcn_rcpf(1.f + __expf(-af));
        f_keep[r] = f;
        store_pair(Gwr + stoff[r], tag1, h_keep[r] * f);
      }
    }

    // ---- phase 2: poll g(t+1), then g@Wur
    pollq(Grd, tag1, b);
    {
      bf16x8 gh[4], gl[4];
#pragma unroll
      for (int kb = 0; kb < 4; ++kb) mk8(&b[kb * 4], gh[kb], gl[kb]);
#pragma unroll
      for (int ct = 0; ct < 2; ++ct) {
        f32x4 q0 = {0.f, 0.f, 0.f, 0.f}, q1 = q0, q2 = q0;
#pragma unroll
        for (int kb = 0; kb < 4; ++kb) {
          q0 = MFMA16(gh[kb], WB(WQH[ct][kb]), q0);
          q1 = MFMA16(gl[kb], WB(WQH[ct][kb]), q1);
          q2 = MFMA16(gh[kb], WB(WQL[ct][kb]), q2);
        }
        f32x4 qv = axu[ct] + q0 + q1 + q2;
#pragma unroll
        for (int i = 0; i < 4; ++i) red[1][w][ct][kq * 4 + i][dcol] = qv[i];
      }
    }
    __syncthreads();
    if (w == 0) {  // finalize h(t+1); plain fire-and-forget h store
#pragma unroll
      for (int r = 0; r < 4; ++r) {
        const int row = 2 * r + sub;
        float ah = red[1][0][fct][row][fc16] + red[1][1][fct][row][fc16] +
                   red[1][2][fct][row][fc16] + red[1][3][fct][row][fc16] + burv;
        float e2 = __expf(2.f * ah);
        float hc = 1.f - 2.f * __builtin_amdgcn_rcpf(e2 + 1.f);  // tanh
        float hn = h_keep[r] + f_keep[r] * (hc - h_keep[r]);
        h_keep[r] = hn;
        store_pair(Hwr + stoff[r], tag1, hn);
        if (t == Tc - 1) out[(size_t)(g * GR + row) * Uc + c0 + colL] = hn;
      }
    }
  }

  // write back dirty exchange/out lines so the next replay's memset starts
  // from clean state (CP's per-dispatch flush + explicit belt-and-braces)
  __builtin_amdgcn_fence(__ATOMIC_RELEASE, "agent");
}

extern "C" void kernel_launch(void* const* d_in, const int* in_sizes, int n_in,
                              void* d_out, int out_size, void* d_ws, size_t ws_size,
                              hipStream_t stream) {
  const float* x   = (const float*)d_in[0];
  const float* Wk  = (const float*)d_in[1];
  const float* Wr  = (const float*)d_in[2];
  const float* br  = (const float*)d_in[3];
  const float* Wu  = (const float*)d_in[4];
  const float* Wur = (const float*)d_in[5];
  const float* bur = (const float*)d_in[6];
  float* out = (float*)d_out;

  hipMemsetAsync(d_ws, 0, WS_ZERO, stream);  // h0 = 0 (tag 0), all parities

  hipLaunchKernelGGL(mgu_kernel, dim3(NWG), dim3(256), 0, stream,
                     x, Wk, Wr, br, Wu, Wur, bur, (unsigned*)d_ws, out);
}

// Round 10
// 9006.712 us; speedup vs baseline: 5.7691x; 5.7691x over previous
//
#include <hip/hip_runtime.h>

// BasicMGU scan, low-contention IF dataflow.
// 4 batch-groups x 16 REAL rows (no M=16 padding waste); 16 WGs/group each
// owning 32 cols; 4 waves/WG each owning a K-quarter (128). Exchange h and
// g=h*f as (tag16|bf16hi),(tag16|bf16lo) dword pairs at IF scope (sc0 sc1,
// the ONLY visibility mode proven to work cross-CU on gfx950: R5/R6/R9).
// Producer stores fire-and-forget; consumers poll the DATA (detection == data
// arrival) with per-lane early-exit and s_sleep backoff to cut L3/IF poll
// pressure (R9 analysis: continuous wide polls self-throttle the fabric).
// Parity double-buffered slots (slot = step&1) make the ==-tag poll provably
// hang-free. Weights AGPR-pinned; 3-term bf16 MFMA split on recurrent mats.

typedef __bf16 bf16;
typedef __attribute__((ext_vector_type(8))) __bf16 bf16x8;
typedef __attribute__((ext_vector_type(4))) float f32x4;
typedef __attribute__((ext_vector_type(4))) unsigned u32x4;
typedef __attribute__((ext_vector_type(2))) unsigned u32x2;

#define MFMA16(a, b, c) __builtin_amdgcn_mfma_f32_16x16x32_bf16((a), (b), (c), 0, 0, 0)
#define WB(q) __builtin_bit_cast(bf16x8, q)

constexpr int Tc = 1024, Dc = 512, Uc = 512;
constexpr int GRPS = 4, GR = 16, NWG = GRPS * 16;  // 64 WGs

constexpr size_t HPAR = (size_t)GRPS * GR * Uc * 2;  // dwords per parity buffer
constexpr size_t WS_ZERO = 4 * HPAR * 4;             // H[2] + G[2] = 1 MiB

// one lane's 32 values (64 tagged dwords) as 16 dwordx4, IF-coherent
__device__ inline void load16q(const unsigned* p, u32x4 b[16]) {
  asm volatile(
      "global_load_dwordx4 %0,  %16, off sc0 sc1\n\t"
      "global_load_dwordx4 %1,  %16, off offset:16 sc0 sc1\n\t"
      "global_load_dwordx4 %2,  %16, off offset:32 sc0 sc1\n\t"
      "global_load_dwordx4 %3,  %16, off offset:48 sc0 sc1\n\t"
      "global_load_dwordx4 %4,  %16, off offset:256 sc0 sc1\n\t"
      "global_load_dwordx4 %5,  %16, off offset:272 sc0 sc1\n\t"
      "global_load_dwordx4 %6,  %16, off offset:288 sc0 sc1\n\t"
      "global_load_dwordx4 %7,  %16, off offset:304 sc0 sc1\n\t"
      "global_load_dwordx4 %8,  %16, off offset:512 sc0 sc1\n\t"
      "global_load_dwordx4 %9,  %16, off offset:528 sc0 sc1\n\t"
      "global_load_dwordx4 %10, %16, off offset:544 sc0 sc1\n\t"
      "global_load_dwordx4 %11, %16, off offset:560 sc0 sc1\n\t"
      "global_load_dwordx4 %12, %16, off offset:768 sc0 sc1\n\t"
      "global_load_dwordx4 %13, %16, off offset:784 sc0 sc1\n\t"
      "global_load_dwordx4 %14, %16, off offset:800 sc0 sc1\n\t"
      "global_load_dwordx4 %15, %16, off offset:816 sc0 sc1"
      : "=&v"(b[0]), "=&v"(b[1]), "=&v"(b[2]), "=&v"(b[3]),
        "=&v"(b[4]), "=&v"(b[5]), "=&v"(b[6]), "=&v"(b[7]),
        "=&v"(b[8]), "=&v"(b[9]), "=&v"(b[10]), "=&v"(b[11]),
        "=&v"(b[12]), "=&v"(b[13]), "=&v"(b[14]), "=&v"(b[15])
      : "v"(p) : "memory");
}

__device__ inline bool freshq(const u32x4* b, unsigned tag) {
  unsigned acc = 0;
#pragma unroll
  for (int i = 0; i < 16; ++i) {
    u32x4 v = b[i];
    acc |= (v[0] ^ tag) | (v[1] ^ tag) | (v[2] ^ tag) | (v[3] ^ tag);
  }
  return (acc & 0xFFFF0000u) == 0;
}

// data poll: per-lane early exit (fresh lanes stop issuing loads) + backoff
__device__ inline void pollq(const unsigned* p, unsigned tag, u32x4 b[16]) {
  bool ok = false;
  int it = 0;
  for (;;) {
    if (!ok) {
      load16q(p, b);
      asm volatile("s_waitcnt vmcnt(0)" ::: "memory");
      __builtin_amdgcn_sched_barrier(0);  // rule 18
      ok = freshq(b, tag);
    }
    if (__ballot(!ok) == 0) return;
    if (++it >= 2) __builtin_amdgcn_s_sleep(16);  // ~0.43us backoff
  }
}

// quad jj holds [tag|hi(2jj), tag|lo(2jj), tag|hi(2jj+1), tag|lo(2jj+1)]
__device__ inline void mk8(const u32x4* q, bf16x8& fh, bf16x8& fl) {
  union { unsigned d[4]; bf16x8 v; } H, L;
#pragma unroll
  for (int jj = 0; jj < 4; ++jj) {
    H.d[jj] = (q[jj][0] & 0xFFFFu) | (q[jj][2] << 16);
    L.d[jj] = (q[jj][1] & 0xFFFFu) | (q[jj][3] << 16);
  }
  fh = H.v;
  fl = L.v;
}

__device__ inline void store_pair(unsigned* p, unsigned tag, float v) {
  bf16 hi = (bf16)v;
  bf16 lo = (bf16)(v - (float)hi);
  u32x2 d;
  d[0] = tag | (unsigned)__builtin_bit_cast(unsigned short, hi);
  d[1] = tag | (unsigned)__builtin_bit_cast(unsigned short, lo);
  asm volatile("global_store_dwordx2 %0, %1, off sc0 sc1" ::"v"(p), "v"(d) : "memory");
}

__global__ __launch_bounds__(256, 1)
void mgu_kernel(const float* __restrict__ x,
                const float* __restrict__ Wk, const float* __restrict__ Wr,
                const float* __restrict__ br,
                const float* __restrict__ Wu, const float* __restrict__ Wur,
                const float* __restrict__ bur,
                unsigned* __restrict__ ws0, float* __restrict__ out) {
  __shared__ float red[2][4][2][16][16];  // [phase][wave][ct][row][col16]

  unsigned* Hb = ws0;               // H[2][...]
  unsigned* Gb = ws0 + 2 * HPAR;    // G[2][...]

  const int wg = blockIdx.x;
  const int g = wg & 3, cw = wg >> 2;     // 4 groups x 16 col-slices
  const int c0 = cw * 32;
  const int tid = threadIdx.x;
  const int w = tid >> 6, lane = tid & 63;
  const int dcol = lane & 15, kq = lane >> 4;
  const int kbase = w * 128 + kq * 8;     // wave = K-quarter

  // ---- weights into AGPR-pinned registers. Wr/Wur hi+lo; Wk/Wu hi only.
  f32x4 WKH[2][4], WRH[2][4], WRL[2][4], WUH[2][4], WQH[2][4], WQL[2][4];
#pragma unroll
  for (int ct = 0; ct < 2; ++ct) {
    const int col = c0 + ct * 16 + dcol;
#pragma unroll
    for (int kb = 0; kb < 4; ++kb) {
      union { bf16x8 v; f32x4 f; } a_, b_, c_, d_, e_, q_;
#pragma unroll
      for (int j = 0; j < 8; ++j) {
        const size_t ko = (size_t)(kbase + kb * 32 + j) * Uc + col;
        { float v = Wk[ko]; a_.v[j] = (bf16)v; }
        { float v = Wr[ko]; bf16 h0 = (bf16)v; b_.v[j] = h0; c_.v[j] = (bf16)(v - (float)h0); }
        { float v = Wu[ko]; d_.v[j] = (bf16)v; }
        { float v = Wur[ko]; bf16 h0 = (bf16)v; e_.v[j] = h0; q_.v[j] = (bf16)(v - (float)h0); }
      }
      WKH[ct][kb] = a_.f; WRH[ct][kb] = b_.f; WRL[ct][kb] = c_.f;
      WUH[ct][kb] = d_.f; WQH[ct][kb] = e_.f; WQL[ct][kb] = q_.f;
    }
  }
#pragma unroll
  for (int ct = 0; ct < 2; ++ct)
#pragma unroll
    for (int kb = 0; kb < 4; ++kb)
      asm volatile("" : "+a"(WKH[ct][kb]), "+a"(WRH[ct][kb]), "+a"(WRL[ct][kb]),
                       "+a"(WUH[ct][kb]), "+a"(WQH[ct][kb]), "+a"(WQL[ct][kb]));

  // ---- finalizer: wave w owns rows 4w..4w+3; lane -> (colL, rows 4w+2r+sub)
  const int sub = lane >> 5, colL = lane & 31;
  const int fct = colL >> 4, fc16 = colL & 15;
  const float brv = br[c0 + colL], burv = bur[c0 + colL];

  const size_t ldoff = ((size_t)(g * GR + dcol) * Uc + kbase) * 2;  // row=dcol
  size_t stoff[2];
#pragma unroll
  for (int r = 0; r < 2; ++r)
    stoff[r] = ((size_t)(g * GR + 4 * w + 2 * r + sub) * Uc + c0 + colL) * 2;

  const float* xptr = x + (size_t)(g * GR + dcol) * Tc * Dc + kbase;

  float h_keep[2] = {0.f, 0.f}, f_keep[2];
  f32x4 axk[2], axu[2];
  f32x4 xr[8];

  auto do_x_mfma = [&]() {  // x(t) in xr -> axk/axu
    bf16x8 xh[4], xl[4];
#pragma unroll
    for (int kb = 0; kb < 4; ++kb) {
      f32x4 a = xr[2 * kb], b = xr[2 * kb + 1];
#pragma unroll
      for (int j = 0; j < 4; ++j) {
        bf16 h0 = (bf16)a[j]; xh[kb][j] = h0; xl[kb][j] = (bf16)(a[j] - (float)h0);
        bf16 h1 = (bf16)b[j]; xh[kb][4 + j] = h1; xl[kb][4 + j] = (bf16)(b[j] - (float)h1);
      }
    }
#pragma unroll
    for (int ct = 0; ct < 2; ++ct) {
      f32x4 k0 = {0.f, 0.f, 0.f, 0.f}, k1 = k0, u0 = k0, u1 = k0;
#pragma unroll
      for (int kb = 0; kb < 4; ++kb) {
        k0 = MFMA16(xh[kb], WB(WKH[ct][kb]), k0);
        k1 = MFMA16(xl[kb], WB(WKH[ct][kb]), k1);
        u0 = MFMA16(xh[kb], WB(WUH[ct][kb]), u0);
        u1 = MFMA16(xl[kb], WB(WUH[ct][kb]), u1);
      }
      axk[ct] = k0 + k1;
      axu[ct] = u0 + u1;
    }
  };

  {  // prologue: x(0) loads
    const float* xp = xptr;
#pragma unroll
    for (int kb = 0; kb < 4; ++kb) {
      xr[2 * kb] = *(const f32x4*)(xp + kb * 32);
      xr[2 * kb + 1] = *(const f32x4*)(xp + kb * 32 + 4);
    }
  }

  for (int t = 0; t < Tc; ++t) {
    const unsigned tag0 = (unsigned)t << 16, tag1 = (unsigned)(t + 1) << 16;
    const unsigned* Hrd = Hb + (size_t)(t & 1) * HPAR + ldoff;
    const unsigned* Grd = Gb + (size_t)((t + 1) & 1) * HPAR + ldoff;
    unsigned* Gwr = Gb + (size_t)((t + 1) & 1) * HPAR;
    unsigned* Hwr = Hb + (size_t)((t + 1) & 1) * HPAR;
    u32x4 b[16];

    // ---- phase 1: poll h(t), x(t) MFMAs, issue x(t+1), h@Wr
    pollq(Hrd, tag0, b);
    do_x_mfma();                     // x(t) -> axk/axu (frees xr)
    if (t + 1 < Tc) {                // x(t+1) into xr; drains during phase 2
      const float* xp = xptr + (size_t)(t + 1) * Dc;
#pragma unroll
      for (int kb = 0; kb < 4; ++kb) {
        xr[2 * kb] = *(const f32x4*)(xp + kb * 32);
        xr[2 * kb + 1] = *(const f32x4*)(xp + kb * 32 + 4);
      }
    }
    {
      bf16x8 fh[4], fl[4];
#pragma unroll
      for (int kb = 0; kb < 4; ++kb) mk8(&b[kb * 4], fh[kb], fl[kb]);
#pragma unroll
      for (int ct = 0; ct < 2; ++ct) {
        f32x4 r0 = {0.f, 0.f, 0.f, 0.f}, r1 = r0, r2 = r0;
#pragma unroll
        for (int kb = 0; kb < 4; ++kb) {
          r0 = MFMA16(fh[kb], WB(WRH[ct][kb]), r0);
          r1 = MFMA16(fl[kb], WB(WRH[ct][kb]), r1);
          r2 = MFMA16(fh[kb], WB(WRL[ct][kb]), r2);
        }
        f32x4 r = axk[ct] + r0 + r1 + r2;
#pragma unroll
        for (int i = 0; i < 4; ++i) red[0][w][ct][kq * 4 + i][dcol] = r[i];
      }
    }
    __syncthreads();
    {  // wave w finalizes rows 4w+2r+sub (2 per lane); fire-and-forget g store
#pragma unroll
      for (int r = 0; r < 2; ++r) {
        const int row = 4 * w + 2 * r + sub;
        float af = red[0][0][fct][row][fc16] + red[0][1][fct][row][fc16] +
                   red[0][2][fct][row][fc16] + red[0][3][fct][row][fc16] + brv;
        float f = __builtin_amdgcn_rcpf(1.f + __expf(-af));
        f_keep[r] = f;
        store_pair(Gwr + stoff[r], tag1, h_keep[r] * f);
      }
    }

    // ---- phase 2: poll g(t+1), g@Wur
    pollq(Grd, tag1, b);
    {
      bf16x8 gh[4], gl[4];
#pragma unroll
      for (int kb = 0; kb < 4; ++kb) mk8(&b[kb * 4], gh[kb], gl[kb]);
#pragma unroll
      for (int ct = 0; ct < 2; ++ct) {
        f32x4 q0 = {0.f, 0.f, 0.f, 0.f}, q1 = q0, q2 = q0;
#pragma unroll
        for (int kb = 0; kb < 4; ++kb) {
          q0 = MFMA16(gh[kb], WB(WQH[ct][kb]), q0);
          q1 = MFMA16(gl[kb], WB(WQH[ct][kb]), q1);
          q2 = MFMA16(gh[kb], WB(WQL[ct][kb]), q2);
        }
        f32x4 qv = axu[ct] + q0 + q1 + q2;
#pragma unroll
        for (int i = 0; i < 4; ++i) red[1][w][ct][kq * 4 + i][dcol] = qv[i];
      }
    }
    __syncthreads();
    {  // finalize h(t+1) for rows 4w+2r+sub; fire-and-forget h store
#pragma unroll
      for (int r = 0; r < 2; ++r) {
        const int row = 4 * w + 2 * r + sub;
        float ah = red[1][0][fct][row][fc16] + red[1][1][fct][row][fc16] +
                   red[1][2][fct][row][fc16] + red[1][3][fct][row][fc16] + burv;
        float e2 = __expf(2.f * ah);
        float hc = 1.f - 2.f * __builtin_amdgcn_rcpf(e2 + 1.f);  // tanh
        float hn = h_keep[r] + f_keep[r] * (hc - h_keep[r]);
        h_keep[r] = hn;
        store_pair(Hwr + stoff[r], tag1, hn);
        if (t == Tc - 1) out[(size_t)(g * GR + row) * Uc + c0 + colL] = hn;
      }
    }
  }
}

extern "C" void kernel_launch(void* const* d_in, const int* in_sizes, int n_in,
                              void* d_out, int out_size, void* d_ws, size_t ws_size,
                              hipStream_t stream) {
  const float* x   = (const float*)d_in[0];
  const float* Wk  = (const float*)d_in[1];
  const float* Wr  = (const float*)d_in[2];
  const float* br  = (const float*)d_in[3];
  const float* Wu  = (const float*)d_in[4];
  const float* Wur = (const float*)d_in[5];
  const float* bur = (const float*)d_in[6];
  float* out = (float*)d_out;

  hipMemsetAsync(d_ws, 0, WS_ZERO, stream);  // h0 = 0 (tag 0), all parities

  hipLaunchKernelGGL(mgu_kernel, dim3(NWG), dim3(256), 0, stream,
                     x, Wk, Wr, br, Wu, Wur, bur, (unsigned*)d_ws, out);
}

// Round 13
// 8156.234 us; speedup vs baseline: 6.3706x; 1.1043x over previous
//
#include <hip/hip_runtime.h>

// BasicMGU scan — R8 protocol (proven 8.3 ms) + spread finalize + disjoint tags.
// 8 batch-groups x 8 rows; 16 WGs/group each owning 32 cols; 4 waves/WG each
// owning a K-quarter. Exchange h and g=h*f as (tag16|bf16hi),(tag16|bf16lo)
// dword pairs at IF scope (sc0 sc1 — the only proven cross-CU visibility mode
// on gfx950: R5/R6/R9). Producer stores fire-and-forget, exactly 1 per lane
// (wave w finalizes rows {2w,2w+1}). Consumers poll the DATA until all
// embedded tags match (detection IS the data load; vmcnt(0) stop-and-wait —
// counted-vmcnt pipelining abandoned after R11/R12: spill-induced VMEM ops
// corrupt the counting invariant). H tags even (2t), G tags odd (2t+1) so
// stale/un-landed contents can never false-match. Parity double-buffered
// slots (overwrite needs 2-step lead, forbidden by the depth-2 syncthreads
// dependency fan). Weights AGPR-pinned; 3-term bf16 MFMA split (hi/lo) on
// recurrent mats -> absmax ~0.005 vs fp32 ref (4x under threshold).

typedef __bf16 bf16;
typedef __attribute__((ext_vector_type(8))) __bf16 bf16x8;
typedef __attribute__((ext_vector_type(4))) float f32x4;
typedef __attribute__((ext_vector_type(4))) unsigned u32x4;
typedef __attribute__((ext_vector_type(2))) unsigned u32x2;

#define MFMA16(a, b, c) __builtin_amdgcn_mfma_f32_16x16x32_bf16((a), (b), (c), 0, 0, 0)
#define WB(q) __builtin_bit_cast(bf16x8, q)

constexpr int Tc = 1024, Dc = 512, Uc = 512;
constexpr int GRPS = 8, GR = 8, NWG = GRPS * 16;  // 128 WGs

constexpr size_t HPAR = (size_t)GRPS * GR * Uc * 2;  // dwords per parity buffer
constexpr size_t WS_ZERO = 4 * HPAR * 4;             // H[2] + G[2] = 1 MiB

// one lane's 32 values (64 tagged dwords) as 16 dwordx4, IF-coherent
__device__ inline void load16q(const unsigned* p, u32x4 b[16]) {
  asm volatile(
      "global_load_dwordx4 %0,  %16, off sc0 sc1\n\t"
      "global_load_dwordx4 %1,  %16, off offset:16 sc0 sc1\n\t"
      "global_load_dwordx4 %2,  %16, off offset:32 sc0 sc1\n\t"
      "global_load_dwordx4 %3,  %16, off offset:48 sc0 sc1\n\t"
      "global_load_dwordx4 %4,  %16, off offset:256 sc0 sc1\n\t"
      "global_load_dwordx4 %5,  %16, off offset:272 sc0 sc1\n\t"
      "global_load_dwordx4 %6,  %16, off offset:288 sc0 sc1\n\t"
      "global_load_dwordx4 %7,  %16, off offset:304 sc0 sc1\n\t"
      "global_load_dwordx4 %8,  %16, off offset:512 sc0 sc1\n\t"
      "global_load_dwordx4 %9,  %16, off offset:528 sc0 sc1\n\t"
      "global_load_dwordx4 %10, %16, off offset:544 sc0 sc1\n\t"
      "global_load_dwordx4 %11, %16, off offset:560 sc0 sc1\n\t"
      "global_load_dwordx4 %12, %16, off offset:768 sc0 sc1\n\t"
      "global_load_dwordx4 %13, %16, off offset:784 sc0 sc1\n\t"
      "global_load_dwordx4 %14, %16, off offset:800 sc0 sc1\n\t"
      "global_load_dwordx4 %15, %16, off offset:816 sc0 sc1"
      : "=&v"(b[0]), "=&v"(b[1]), "=&v"(b[2]), "=&v"(b[3]),
        "=&v"(b[4]), "=&v"(b[5]), "=&v"(b[6]), "=&v"(b[7]),
        "=&v"(b[8]), "=&v"(b[9]), "=&v"(b[10]), "=&v"(b[11]),
        "=&v"(b[12]), "=&v"(b[13]), "=&v"(b[14]), "=&v"(b[15])
      : "v"(p) : "memory");
}

__device__ inline bool freshq(const u32x4* b, unsigned tag) {
  unsigned acc = 0;
#pragma unroll
  for (int i = 0; i < 16; ++i) {
    u32x4 v = b[i];
    acc |= (v[0] ^ tag) | (v[1] ^ tag) | (v[2] ^ tag) | (v[3] ^ tag);
  }
  return (acc & 0xFFFF0000u) == 0;
}

// direct data poll: when it breaks, the data is already in b[]
__device__ inline void pollq(const unsigned* p, unsigned tag, u32x4 b[16]) {
  for (;;) {
    load16q(p, b);
    asm volatile("s_waitcnt vmcnt(0)" ::: "memory");
    __builtin_amdgcn_sched_barrier(0);  // rule 18
    if (__ballot(!freshq(b, tag)) == 0) break;
  }
}

// quad jj holds [tag|hi(2jj), tag|lo(2jj), tag|hi(2jj+1), tag|lo(2jj+1)]
__device__ inline void mk8(const u32x4* q, bf16x8& fh, bf16x8& fl) {
  union { unsigned d[4]; bf16x8 v; } H, L;
#pragma unroll
  for (int jj = 0; jj < 4; ++jj) {
    H.d[jj] = (q[jj][0] & 0xFFFFu) | (q[jj][2] << 16);
    L.d[jj] = (q[jj][1] & 0xFFFFu) | (q[jj][3] << 16);
  }
  fh = H.v;
  fl = L.v;
}

__device__ inline void store_pair(unsigned* p, unsigned tag, float v) {
  bf16 hi = (bf16)v;
  bf16 lo = (bf16)(v - (float)hi);
  u32x2 d;
  d[0] = tag | (unsigned)__builtin_bit_cast(unsigned short, hi);
  d[1] = tag | (unsigned)__builtin_bit_cast(unsigned short, lo);
  asm volatile("global_store_dwordx2 %0, %1, off sc0 sc1" ::"v"(p), "v"(d) : "memory");
}

__global__ __launch_bounds__(256, 1)
void mgu_kernel(const float* __restrict__ x,
                const float* __restrict__ Wk, const float* __restrict__ Wr,
                const float* __restrict__ br,
                const float* __restrict__ Wu, const float* __restrict__ Wur,
                const float* __restrict__ bur,
                unsigned* __restrict__ ws0, float* __restrict__ out) {
  __shared__ float red[2][4][2][16][16];  // [phase][wave][ct][row][col16]

  unsigned* Hb = ws0;               // H[2][...]
  unsigned* Gb = ws0 + 2 * HPAR;    // G[2][...]

  const int wg = blockIdx.x;
  const int g = wg & 7, cw = wg >> 3;
  const int c0 = cw * 32;
  const int tid = threadIdx.x;
  const int w = tid >> 6, lane = tid & 63;
  const int dcol = lane & 15, kq = lane >> 4;
  const int rrow = dcol & 7;              // real batch row (dup for MFMA M=16)
  const int kbase = w * 128 + kq * 8;

  // ---- weights into AGPR-pinned registers. Wr/Wur hi+lo; Wk/Wu hi only.
  f32x4 WKH[2][4], WRH[2][4], WRL[2][4], WUH[2][4], WQH[2][4], WQL[2][4];
#pragma unroll
  for (int ct = 0; ct < 2; ++ct) {
    const int col = c0 + ct * 16 + dcol;
#pragma unroll
    for (int kb = 0; kb < 4; ++kb) {
      union { bf16x8 v; f32x4 f; } a_, b_, c_, d_, e_, q_;
#pragma unroll
      for (int j = 0; j < 8; ++j) {
        const size_t ko = (size_t)(kbase + kb * 32 + j) * Uc + col;
        { float v = Wk[ko]; a_.v[j] = (bf16)v; }
        { float v = Wr[ko]; bf16 h0 = (bf16)v; b_.v[j] = h0; c_.v[j] = (bf16)(v - (float)h0); }
        { float v = Wu[ko]; d_.v[j] = (bf16)v; }
        { float v = Wur[ko]; bf16 h0 = (bf16)v; e_.v[j] = h0; q_.v[j] = (bf16)(v - (float)h0); }
      }
      WKH[ct][kb] = a_.f; WRH[ct][kb] = b_.f; WRL[ct][kb] = c_.f;
      WUH[ct][kb] = d_.f; WQH[ct][kb] = e_.f; WQL[ct][kb] = q_.f;
    }
  }
#pragma unroll
  for (int ct = 0; ct < 2; ++ct)
#pragma unroll
    for (int kb = 0; kb < 4; ++kb)
      asm volatile("" : "+a"(WKH[ct][kb]), "+a"(WRH[ct][kb]), "+a"(WRL[ct][kb]),
                       "+a"(WUH[ct][kb]), "+a"(WQH[ct][kb]), "+a"(WQL[ct][kb]));

  // ---- spread finalizer: wave w owns rows {2w, 2w+1}; exactly 1 value/lane
  const int sub = lane >> 5, colL = lane & 31;
  const int fct = colL >> 4, fc16 = colL & 15;
  const int frow = 2 * w + sub;
  const float brv = br[c0 + colL], burv = bur[c0 + colL];

  const size_t ldoff = ((size_t)(g * GR + rrow) * Uc + kbase) * 2;
  const size_t stoff = ((size_t)(g * GR + frow) * Uc + c0 + colL) * 2;

  const float* xptr = x + (size_t)(g * GR + rrow) * Tc * Dc + kbase;

  float h_keep = 0.f, f_keep = 0.f;
  f32x4 axk[2], axu[2];
  f32x4 xr[8];

  auto do_x_mfma = [&]() {
    bf16x8 xh[4], xl[4];
#pragma unroll
    for (int kb = 0; kb < 4; ++kb) {
      f32x4 a = xr[2 * kb], b = xr[2 * kb + 1];
#pragma unroll
      for (int j = 0; j < 4; ++j) {
        bf16 h0 = (bf16)a[j]; xh[kb][j] = h0; xl[kb][j] = (bf16)(a[j] - (float)h0);
        bf16 h1 = (bf16)b[j]; xh[kb][4 + j] = h1; xl[kb][4 + j] = (bf16)(b[j] - (float)h1);
      }
    }
#pragma unroll
    for (int ct = 0; ct < 2; ++ct) {
      f32x4 k0 = {0.f, 0.f, 0.f, 0.f}, k1 = k0, u0 = k0, u1 = k0;
#pragma unroll
      for (int kb = 0; kb < 4; ++kb) {
        k0 = MFMA16(xh[kb], WB(WKH[ct][kb]), k0);
        k1 = MFMA16(xl[kb], WB(WKH[ct][kb]), k1);
        u0 = MFMA16(xh[kb], WB(WUH[ct][kb]), u0);
        u1 = MFMA16(xl[kb], WB(WUH[ct][kb]), u1);
      }
      axk[ct] = k0 + k1;
      axu[ct] = u0 + u1;
    }
  };

  {  // prologue: x(0) loads + convert + x-MFMAs
    const float* xp = xptr;
#pragma unroll
    for (int kb = 0; kb < 4; ++kb) {
      xr[2 * kb] = *(const f32x4*)(xp + kb * 32);
      xr[2 * kb + 1] = *(const f32x4*)(xp + kb * 32 + 4);
    }
    do_x_mfma();
  }

  for (int t = 0; t < Tc; ++t) {
    const unsigned tagH  = (unsigned)(2 * t) << 16;       // even
    const unsigned tagG  = (unsigned)(2 * t + 1) << 16;   // odd
    const unsigned tagH1 = (unsigned)(2 * t + 2) << 16;
    const unsigned* Hrd = Hb + (size_t)(t & 1) * HPAR + ldoff;
    const unsigned* Grd = Gb + (size_t)((t + 1) & 1) * HPAR + ldoff;
    unsigned* Gwr = Gb + (size_t)((t + 1) & 1) * HPAR;
    unsigned* Hwr = Hb + (size_t)((t + 1) & 1) * HPAR;
    u32x4 b[16];

    // ---- phase 1: a_f = x@Wk (done) + h@Wr; poll h(t) data directly
    pollq(Hrd, tagH, b);
    if (t + 1 < Tc) {  // x(t+1) prefetch: drains during phase-2 poll
      const float* xp = xptr + (size_t)(t + 1) * Dc;
#pragma unroll
      for (int kb = 0; kb < 4; ++kb) {
        xr[2 * kb] = *(const f32x4*)(xp + kb * 32);
        xr[2 * kb + 1] = *(const f32x4*)(xp + kb * 32 + 4);
      }
    }
    {
      bf16x8 fh[4], fl[4];
#pragma unroll
      for (int kb = 0; kb < 4; ++kb) mk8(&b[kb * 4], fh[kb], fl[kb]);
#pragma unroll
      for (int ct = 0; ct < 2; ++ct) {
        f32x4 r0 = {0.f, 0.f, 0.f, 0.f}, r1 = r0, r2 = r0;
#pragma unroll
        for (int kb = 0; kb < 4; ++kb) {
          r0 = MFMA16(fh[kb], WB(WRH[ct][kb]), r0);
          r1 = MFMA16(fl[kb], WB(WRH[ct][kb]), r1);
          r2 = MFMA16(fh[kb], WB(WRL[ct][kb]), r2);
        }
        f32x4 r = axk[ct] + r0 + r1 + r2;
#pragma unroll
        for (int i = 0; i < 4; ++i) red[0][w][ct][kq * 4 + i][dcol] = r[i];
      }
    }
    __syncthreads();
    {  // finalize f for this lane's (frow, colL); fire-and-forget g store
      float af = red[0][0][fct][frow][fc16] + red[0][1][fct][frow][fc16] +
                 red[0][2][fct][frow][fc16] + red[0][3][fct][frow][fc16] + brv;
      float f = __builtin_amdgcn_rcpf(1.f + __expf(-af));
      f_keep = f;
      store_pair(Gwr + stoff, tagG, h_keep * f);
    }

    // ---- phase 2: a_h = x@Wu (done) + g@Wur; poll g data directly
    pollq(Grd, tagG, b);
    {
      bf16x8 gh[4], gl[4];
#pragma unroll
      for (int kb = 0; kb < 4; ++kb) mk8(&b[kb * 4], gh[kb], gl[kb]);
#pragma unroll
      for (int ct = 0; ct < 2; ++ct) {
        f32x4 q0 = {0.f, 0.f, 0.f, 0.f}, q1 = q0, q2 = q0;
#pragma unroll
        for (int kb = 0; kb < 4; ++kb) {
          q0 = MFMA16(gh[kb], WB(WQH[ct][kb]), q0);
          q1 = MFMA16(gl[kb], WB(WQH[ct][kb]), q1);
          q2 = MFMA16(gh[kb], WB(WQL[ct][kb]), q2);
        }
        f32x4 qv = axu[ct] + q0 + q1 + q2;
#pragma unroll
        for (int i = 0; i < 4; ++i) red[1][w][ct][kq * 4 + i][dcol] = qv[i];
      }
    }
    __syncthreads();
    {  // finalize h(t+1); fire-and-forget h store
      float ah = red[1][0][fct][frow][fc16] + red[1][1][fct][frow][fc16] +
                 red[1][2][fct][frow][fc16] + red[1][3][fct][frow][fc16] + burv;
      float e2 = __expf(2.f * ah);
      float hc = 1.f - 2.f * __builtin_amdgcn_rcpf(e2 + 1.f);  // tanh
      float hn = h_keep + f_keep * (hc - h_keep);
      h_keep = hn;
      store_pair(Hwr + stoff, tagH1, hn);
      if (t == Tc - 1) out[(size_t)(g * GR + frow) * Uc + c0 + colL] = hn;
    }
    if (t + 1 < Tc) do_x_mfma();  // x(t+1) convert + x-MFMAs off the wait path
  }
}

extern "C" void kernel_launch(void* const* d_in, const int* in_sizes, int n_in,
                              void* d_out, int out_size, void* d_ws, size_t ws_size,
                              hipStream_t stream) {
  const float* x   = (const float*)d_in[0];
  const float* Wk  = (const float*)d_in[1];
  const float* Wr  = (const float*)d_in[2];
  const float* br  = (const float*)d_in[3];
  const float* Wu  = (const float*)d_in[4];
  const float* Wur = (const float*)d_in[5];
  const float* bur = (const float*)d_in[6];
  float* out = (float*)d_out;

  hipMemsetAsync(d_ws, 0, WS_ZERO, stream);  // h0 = 0 (tag 0 = H even), parities

  hipLaunchKernelGGL(mgu_kernel, dim3(NWG), dim3(256), 0, stream,
                     x, Wk, Wr, br, Wu, Wur, bur, (unsigned*)d_ws, out);
}